// Round 6
// baseline (1603.694 us; speedup 1.0000x reference)
//
#include <hip/hip_runtime.h>

// ---------------------------------------------------------------------------
// Earth-specific transformer block (Pangu/swin style) for MI355X gfx950.
// DIM=192, HEADS=6 (d=32), RES=(8,96,180), WIN=(2,6,12), SHIFT=(1,3,6), MLP=4x
// All GEMMs in bf16 MFMA (16x16x32), fp32 accumulate. Output fp32.
// R6: GEMM restructured for skinny-K — A-fragments stream directly from
//     global (per-lane base ptrs, folded offsets, 1-deep prefetch; re-reads
//     are L1/L2/L3 hits), B staged full-K (36 KB) ONCE per N-tile via
//     global_load_lds + XOR slot swizzle. Staged bytes cut ~4x, one vmcnt
//     drain per N-tile instead of three. LDS 36.9KB -> 4 blocks/CU.
//     attn unchanged from R5 (control).
// ---------------------------------------------------------------------------

typedef __attribute__((ext_vector_type(8))) short short8;
typedef __attribute__((ext_vector_type(4))) short short4v;
typedef __attribute__((ext_vector_type(4))) float floatx4;
typedef unsigned short bfu;   // raw bf16 bits

#define GLOAD_LDS16(g, l)                                            \
  __builtin_amdgcn_global_load_lds(                                  \
      (const __attribute__((address_space(1))) unsigned int*)(g),    \
      (__attribute__((address_space(3))) unsigned int*)(l), 16, 0, 0)

__device__ __forceinline__ bfu f2bf(float f) {
  unsigned int u = __builtin_bit_cast(unsigned int, f);
  u += 0x7fffu + ((u >> 16) & 1u);        // round-to-nearest-even
  return (bfu)(u >> 16);
}
__device__ __forceinline__ float bf2f(bfu s) {
  return __builtin_bit_cast(float, (unsigned int)s << 16);
}

// --- transpose fp32 (K x N) -> bf16 (N x K) --------------------------------
__global__ void wt_kernel(const float* __restrict__ src, bfu* __restrict__ dst,
                          int K, int N) {
  int idx = blockIdx.x * 256 + threadIdx.x;
  if (idx >= K * N) return;
  int k = idx / N, n = idx % N;
  dst[(size_t)n * K + k] = f2bf(src[idx]);
}

// --- compact bias: tblT[h][w][3312] bf16 from table[ep][w][h] fp32 ---------
__global__ void bias2_kernel(const float* __restrict__ table,
                             bfu* __restrict__ out) {
  int idx = blockIdx.x * 256 + threadIdx.x;
  if (idx >= 1271808) return;                    // 6*64*3312
  int h = idx / 211968;
  int r = idx % 211968;
  int w = r / 3312, ep = r % 3312;
  out[idx] = f2bf(table[(size_t)ep * 384 + w * 6 + h]);
}

// --- zero the m=144..159 pad columns of the transposed V buffer ------------
__global__ void vpad_kernel(unsigned int* __restrict__ vbw) {
  int tid = threadIdx.x;
  int dd = tid >> 3, c = tid & 7;
  vbw[(size_t)blockIdx.x * 2560 + dd * 80 + 72 + c] = 0;
}

// --- LN1 + roll(-shift) + window-partition gather -> bf16 A1 ---------------
__global__ __launch_bounds__(256) void ln1_kernel(
    const float* __restrict__ x, const float* __restrict__ g,
    const float* __restrict__ be, bfu* __restrict__ A1) {
  int wv = threadIdx.x >> 6, lane = threadIdx.x & 63;
  int r = blockIdx.x * 4 + wv;
  int n = r % 144, w = (r / 144) & 63, bb = r / 9216;
  int ip = w >> 4, il = w & 15;
  int p1 = n / 72, rem = n % 72, l1 = rem / 12, o1 = rem % 12;
  int pl = ip * 2 + p1 + 1;   if (pl >= 8) pl -= 8;     // rolled pos + shift
  int lat = il * 6 + l1 + 3;  if (lat >= 96) lat -= 96;
  int lon = bb * 12 + o1 + 6; if (lon >= 180) lon -= 180;
  size_t t = (size_t)(pl * 96 + lat) * 180 + lon;
  const float* xr = x + t * 192;
  float v0 = xr[lane], v1 = xr[lane + 64], v2 = xr[lane + 128];
  float s = v0 + v1 + v2;
  #pragma unroll
  for (int o = 32; o; o >>= 1) s += __shfl_xor(s, o);
  float mu = s * (1.0f / 192.0f);
  float d0 = v0 - mu, d1 = v1 - mu, d2 = v2 - mu;
  float q2 = d0 * d0 + d1 * d1 + d2 * d2;
  #pragma unroll
  for (int o = 32; o; o >>= 1) q2 += __shfl_xor(q2, o);
  float rstd = rsqrtf(q2 * (1.0f / 192.0f) + 1e-5f);
  bfu* orow = A1 + (size_t)r * 192;
  orow[lane]       = f2bf(d0 * rstd * g[lane]       + be[lane]);
  orow[lane + 64]  = f2bf(d1 * rstd * g[lane + 64]  + be[lane + 64]);
  orow[lane + 128] = f2bf(d2 * rstd * g[lane + 128] + be[lane + 128]);
}

// --- LN2 (natural rows) -> bf16 --------------------------------------------
__global__ __launch_bounds__(256) void ln2_kernel(
    const float* __restrict__ xin, const float* __restrict__ g,
    const float* __restrict__ be, bfu* __restrict__ yout) {
  int wv = threadIdx.x >> 6, lane = threadIdx.x & 63;
  size_t r = (size_t)blockIdx.x * 4 + wv;
  const float* xr = xin + r * 192;
  float v0 = xr[lane], v1 = xr[lane + 64], v2 = xr[lane + 128];
  float s = v0 + v1 + v2;
  #pragma unroll
  for (int o = 32; o; o >>= 1) s += __shfl_xor(s, o);
  float mu = s * (1.0f / 192.0f);
  float d0 = v0 - mu, d1 = v1 - mu, d2 = v2 - mu;
  float q2 = d0 * d0 + d1 * d1 + d2 * d2;
  #pragma unroll
  for (int o = 32; o; o >>= 1) q2 += __shfl_xor(q2, o);
  float rstd = rsqrtf(q2 * (1.0f / 192.0f) + 1e-5f);
  bfu* orow = yout + r * 192;
  orow[lane]       = f2bf(d0 * rstd * g[lane]       + be[lane]);
  orow[lane + 64]  = f2bf(d1 * rstd * g[lane + 64]  + be[lane + 64]);
  orow[lane + 128] = f2bf(d2 * rstd * g[lane + 128] + be[lane + 128]);
}

// --- MFMA GEMM: block = 128-row M-panel, loops over NT N-tiles of 96 -------
// 4 waves, wave tile 32x96 (acc[2][6]). A-frags stream from GLOBAL (bases
// precomputed once; kc/ks offsets fold into imm; re-reads L1/L2/L3-hot).
// B staged per (NT, 192-K chunk) into LDS [96][24 slots] via global_load_lds
// with XOR-in-low-3-bits slot swizzle (bank-balanced ds_read_b128).
// mode 0: qkv scatter (+bias): q pre-scaled -> [win][n][32]; k -> same;
//         v TRANSPOSED -> [win][dd][160] (pad cols zeroed by vpad_kernel)
// mode 1: proj (+bias) + un-window/un-roll + residual(aux=x) -> fp32 out0
// mode 2: fc1 (+bias) + exact GELU -> bf16 h [row][768], LDS-staged stores
// mode 3: fc2 (+bias) + residual(aux=x1) -> fp32 out0
__global__ __launch_bounds__(256, 4) void gemm_kernel(
    const bfu* __restrict__ A, const bfu* __restrict__ BT,
    const float* __restrict__ bias, int K, int NT, int mode,
    const float* aux, void* out0, void* out1, void* out2) {
  __shared__ __align__(16) short Bs[96 * 192];   // 36 KB (unioned with E)
  bfu* E = (bfu*)Bs;                             // epilogue tile [128][104]
  const int tid = threadIdx.x;
  const int wv = tid >> 6, lane = tid & 63;
  const int r16 = lane & 15, quad = lane >> 4;
  const int sw = r16 & 7;                        // read-side XOR key
  const int m0 = blockIdx.x * 128;

  const short* Arow[2];
  #pragma unroll
  for (int s = 0; s < 2; ++s)
    Arow[s] = (const short*)A + (size_t)(m0 + wv * 32 + s * 16 + r16) * K + quad * 8;

  for (int xt = 0; xt < NT; ++xt) {
    const int n0 = xt * 96;
    const bfu* Bsrc = BT + (size_t)n0 * K;

    floatx4 acc[2][6];
    #pragma unroll
    for (int s = 0; s < 2; ++s)
      #pragma unroll
      for (int j = 0; j < 6; ++j) acc[s][j] = (floatx4){0.f, 0.f, 0.f, 0.f};

    for (int kc = 0; kc < K; kc += 192) {
      __syncthreads();                 // prev chunk/E fully read
      // stage B chunk [96][192]: 2304 16B chunks, 9/thread, swizzled source
      #pragma unroll
      for (int j = 0; j < 9; ++j) {
        int c = j * 256 + tid;
        int row = c / 24, sl = c % 24;
        int l = (sl & ~7) | ((sl ^ row) & 7);
        GLOAD_LDS16(Bsrc + (size_t)row * K + kc + l * 8, Bs + c * 8);
      }
      __syncthreads();                 // drain -> B ready

      // K-inner: A from global (1-deep prefetch), B from LDS (swizzled read)
      short8 a0 = *(const short8*)(Arow[0] + kc);
      short8 a1 = *(const short8*)(Arow[1] + kc);
      #pragma unroll
      for (int ks = 0; ks < 6; ++ks) {
        short8 n0a, n1a;
        if (ks < 5) {
          n0a = *(const short8*)(Arow[0] + kc + (ks + 1) * 32);
          n1a = *(const short8*)(Arow[1] + kc + (ks + 1) * 32);
        }
        short8 b[6];
        const int s_log = ks * 4 + quad;
        const int phys = (s_log & ~7) | ((s_log ^ sw) & 7);
        #pragma unroll
        for (int j = 0; j < 6; ++j)
          b[j] = *(const short8*)(Bs + (j * 16 + r16) * 192 + phys * 8);
        #pragma unroll
        for (int j = 0; j < 6; ++j) {
          acc[0][j] = __builtin_amdgcn_mfma_f32_16x16x32_bf16(a0, b[j], acc[0][j], 0, 0, 0);
          acc[1][j] = __builtin_amdgcn_mfma_f32_16x16x32_bf16(a1, b[j], acc[1][j], 0, 0, 0);
        }
        a0 = n0a; a1 = n1a;
      }
    }

    if (mode == 0 || mode == 2) {
      // ---- stage epilogue tile in LDS (bf16), then coalesced 16B stores ----
      __syncthreads();                 // all waves done reading Bs
      #pragma unroll
      for (int s = 0; s < 2; ++s) {
        int er = wv * 32 + s * 16 + quad * 4;
        #pragma unroll
        for (int j = 0; j < 6; ++j) {
          int c = j * 16 + r16;
          float bia = bias[n0 + c];
          #pragma unroll
          for (int i = 0; i < 4; ++i) {
            float val = acc[s][j][i] + bia;
            if (mode == 0) {
              if (n0 < 192) val *= 0.17677669529663687f;   // q pre-scale
              E[(er + i) * 104 + c] = f2bf(val);
            } else {
              float ge = 0.5f * val * (1.0f + erff(val * 0.70710678118654752f));
              E[(er + i) * 104 + c] = f2bf(ge);
            }
          }
        }
      }
      __syncthreads();
      if (mode == 2) {
        // h[row][768], 16B chunks: 128 rows x 12 chunks = 1536
        #pragma unroll
        for (int u = 0; u < 6; ++u) {
          int id = u * 256 + tid;
          int r = id / 12, c8 = (id % 12) * 8;
          *(short8*)((bfu*)out0 + (size_t)(m0 + r) * 768 + n0 + c8) =
              *(const short8*)(E + r * 104 + c8);
        }
      } else if (n0 < 384) {
        // q or k: [win][n][32], 16B chunks along dd
        bfu* dst = (bfu*)(n0 < 192 ? out0 : out1);
        #pragma unroll
        for (int u = 0; u < 6; ++u) {
          int id = u * 256 + tid;
          int r = id / 12, c8 = (id % 12) * 8;
          int row = m0 + r;
          int n = row % 144, w = (row / 144) & 63, bb = row / 9216;
          int head = ((n0 + c8) % 192) >> 5, dd = c8 & 31;
          size_t win = (size_t)(bb * 6 + head) * 64 + w;
          *(short8*)(dst + win * 4608 + n * 32 + dd) =
              *(const short8*)(E + r * 104 + c8);
        }
      } else {
        // v transposed: [win][dd][160], 16B chunks along n (8 rows of E)
        #pragma unroll
        for (int u = 0; u < 6; ++u) {
          int id = u * 256 + tid;
          int c = id % 96, k8 = id / 96;
          int r0 = k8 * 8;
          int row0 = m0 + r0;
          int n = row0 % 144, w = (row0 / 144) & 63, bb = row0 / 9216;
          int head = ((n0 + c) % 192) >> 5, dd = c & 31;
          size_t win = (size_t)(bb * 6 + head) * 64 + w;
          short8 t8;
          #pragma unroll
          for (int i = 0; i < 8; ++i) t8[i] = (short)E[(r0 + i) * 104 + c];
          *(short8*)((bfu*)out2 + win * 5120 + dd * 160 + n) = t8;
        }
      }
    } else {
      // ---- direct fp32 epilogue (modes 1 and 3): 64B quad-chunk stores ----
      #pragma unroll
      for (int s = 0; s < 2; ++s) {
        const int row0 = m0 + wv * 32 + s * 16 + quad * 4;
        #pragma unroll
        for (int j = 0; j < 6; ++j) {
          int col = n0 + j * 16 + r16;
          float bia = bias[col];
          #pragma unroll
          for (int i = 0; i < 4; ++i) {
            int row = row0 + i;
            float val = acc[s][j][i] + bia;
            if (mode == 1) {
              int n = row % 144, w = (row / 144) & 63, bb = row / 9216;
              int ip = w >> 4, il = w & 15;
              int p1 = n / 72, rem = n % 72, l1 = rem / 12, o1 = rem % 12;
              int pl = ip * 2 + p1 + 1;   if (pl >= 8) pl -= 8;
              int lat = il * 6 + l1 + 3;  if (lat >= 96) lat -= 96;
              int lon = bb * 12 + o1 + 6; if (lon >= 180) lon -= 180;
              size_t t = (size_t)(pl * 96 + lat) * 180 + lon;
              ((float*)out0)[t * 192 + col] = aux[t * 192 + col] + val;
            } else {
              size_t idx = (size_t)row * 192 + col;
              ((float*)out0)[idx] = aux[idx] + val;
            }
          }
        }
      }
    }
  }
}

// --- windowed attention: one block per (b, head-pair, w) --------------------
// (unchanged from R5)
__global__ __launch_bounds__(256) void attn_kernel(
    const bfu* __restrict__ qg_, const bfu* __restrict__ kg_,
    const bfu* __restrict__ vg_, const bfu* __restrict__ tblT,
    bfu* __restrict__ aout) {
  __shared__ __align__(16) bfu Ss[144 * 148];   // 42.6 KB
  __shared__ __align__(16) bfu bias_l[3312];    // 6.6 KB slice
  __shared__ unsigned short rn[144];            // row bias index part
  __shared__ short cm[144];                     // col bias index part
  __shared__ unsigned char regs[144];           // shift-mask region ids

  const int w = blockIdx.x, h0 = blockIdx.y * 2, b = blockIdx.z;
  const int tid = threadIdx.x;
  const int wv = tid >> 6, lane = tid & 63, r16 = lane & 15, quad = lane >> 4;

  if (tid < 144) {
    int n = tid;
    int p1 = n / 72, rem = n % 72, l1 = rem / 12, o1 = rem % 12;
    rn[n] = (unsigned short)(828 * p1 + 23 * l1 + o1 + 11);
    cm[n] = (short)(1656 * p1 + 138 * l1 - o1);
    int ip = w >> 4, il = w & 15;
    int pl = ip * 2 + p1, lat = il * 6 + l1, lon = b * 12 + o1;
    int rp = pl < 6 ? 0 : (pl < 7 ? 1 : 2);
    int rl = lat < 90 ? 0 : (lat < 93 ? 1 : 2);
    int ro = lon < 174 ? 0 : 1;
    regs[n] = (unsigned char)(rp * 9 + rl * 3 + ro);
  }

  // async-stage bias slice for head h0 (414 x 16B chunks)
  {
    const bfu* bsrc = tblT + (size_t)(h0 * 64 + w) * 3312;
    GLOAD_LDS16(bsrc + tid * 8, bias_l + tid * 8);
    if (tid < 158) GLOAD_LDS16(bsrc + (256 + tid) * 8, bias_l + (256 + tid) * 8);
  }

  short4v ov[2][5];
  #pragma unroll
  for (int hh = 0; hh < 2; ++hh) {
    const int h = h0 + hh;
    const size_t win = (size_t)((b * 6 + h) * 64 + w);
    const bfu* qg = qg_ + win * 4608;
    const bfu* kg = kg_ + win * 4608;
    const bfu* vt = vg_ + win * 5120;

    // Phase 1: S = Q K^T (Q pre-scaled). 81 tiles.
    #pragma unroll 3
    for (int u = 0; u < 21; ++u) {
      int t = wv * 21 + u;
      if (t < 81) {
        int tn = t / 9, tm = t % 9;
        short8 a  = *(const short8*)(qg + (tn * 16 + r16) * 32 + quad * 8);
        short8 bo = *(const short8*)(kg + (tm * 16 + r16) * 32 + quad * 8);
        floatx4 z = (floatx4){0.f, 0.f, 0.f, 0.f};
        floatx4 d = __builtin_amdgcn_mfma_f32_16x16x32_bf16(a, bo, z, 0, 0, 0);
        int m = tm * 16 + r16;
        #pragma unroll
        for (int i = 0; i < 4; ++i)
          Ss[(tn * 16 + quad * 4 + i) * 148 + m] = f2bf(d[i]);
      }
    }
    __syncthreads();   // S ready; bias slice loaded; tables ready

    // Phase 2: softmax + bias(LDS) + mask.
    for (int rb = 0; rb < 9; ++rb) {
      int rr = rb * 16 + wv * 4 + quad;
      unsigned char rgn = regs[rr];
      int rnv = rn[rr];
      const bfu* srow = Ss + rr * 148;
      float v[9];
      float mx = -1e30f;
      #pragma unroll
      for (int j = 0; j < 9; ++j) {
        int c = r16 + 16 * j;
        float s = bf2f(srow[c]) + bf2f(bias_l[rnv + cm[c]]);
        if (regs[c] != rgn) s -= 100.0f;
        v[j] = s;
        mx = fmaxf(mx, s);
      }
      #pragma unroll
      for (int o = 8; o; o >>= 1) mx = fmaxf(mx, __shfl_xor(mx, o));
      float sum = 0.f;
      #pragma unroll
      for (int j = 0; j < 9; ++j) { v[j] = __expf(v[j] - mx); sum += v[j]; }
      #pragma unroll
      for (int o = 8; o; o >>= 1) sum += __shfl_xor(sum, o);
      float inv = 1.0f / sum;
      bfu* wrow = Ss + rr * 148;
      #pragma unroll
      for (int j = 0; j < 9; ++j) wrow[r16 + 16 * j] = f2bf(v[j] * inv);
    }
    __syncthreads();   // P ready; bias_l reads done

    if (hh == 0) {     // overlap next head's bias load with PV
      const bfu* bsrc = tblT + (size_t)((h0 + 1) * 64 + w) * 3312;
      GLOAD_LDS16(bsrc + tid * 8, bias_l + tid * 8);
      if (tid < 158) GLOAD_LDS16(bsrc + (256 + tid) * 8, bias_l + (256 + tid) * 8);
    }

    // Phase 3: O = P V, operand-swapped -> D[dd][n]; pack rows as short4.
    short8 bfr[2][5];
    #pragma unroll
    for (int td = 0; td < 2; ++td)
      #pragma unroll
      for (int km = 0; km < 5; ++km)
        bfr[td][km] =
            *(const short8*)(vt + (td * 16 + r16) * 160 + km * 32 + quad * 8);

    #pragma unroll
    for (int u = 0; u < 5; ++u) {
      int t = wv * 5 + u;
      if (t < 18) {
        int tn = t >> 1, td = t & 1;
        floatx4 acc = (floatx4){0.f, 0.f, 0.f, 0.f};
        #pragma unroll
        for (int km = 0; km < 5; ++km) {
          short8 a;
          if (km == 4 && quad >= 2) {
            a = (short8)(short)0;          // P cols 144..159 are zero
          } else {
            const bfu* ap = Ss + (tn * 16 + r16) * 148 + km * 32 + quad * 8;
            *(short4v*)&a       = *(const short4v*)ap;
            *((short4v*)&a + 1) = *(const short4v*)(ap + 4);
          }
          acc = __builtin_amdgcn_mfma_f32_16x16x32_bf16(bfr[td][km], a, acc, 0, 0, 0);
        }
        short4v o;
        #pragma unroll
        for (int i = 0; i < 4; ++i) o[i] = (short)f2bf(acc[i]);
        ov[hh][u] = o;
      }
    }
    if (hh == 0) __syncthreads();   // Ss reads done before next head's phase 1
  }

  // store both heads together: full 128B lines per row
  const size_t orow = (size_t)((b * 64 + w) * 144) * 192 + h0 * 32;
  #pragma unroll
  for (int u = 0; u < 5; ++u) {
    int t = wv * 5 + u;
    if (t < 18) {
      int tn = t >> 1, td = t & 1;
      size_t a0 = orow + (size_t)(tn * 16 + r16) * 192 + td * 16 + quad * 4;
      *(short4v*)(aout + a0)      = ov[0][u];
      *(short4v*)(aout + a0 + 32) = ov[1][u];
    }
  }
}

// ---------------------------------------------------------------------------
extern "C" void kernel_launch(void* const* d_in, const int* in_sizes, int n_in,
                              void* d_out, int out_size, void* d_ws, size_t ws_size,
                              hipStream_t stream) {
  (void)in_sizes; (void)n_in; (void)out_size; (void)ws_size;
  const float* x     = (const float*)d_in[0];
  const float* n1g   = (const float*)d_in[1];
  const float* n1b   = (const float*)d_in[2];
  const float* qkvw  = (const float*)d_in[3];
  const float* qkvb  = (const float*)d_in[4];
  const float* tbl   = (const float*)d_in[5];
  const float* projw = (const float*)d_in[6];
  const float* projb = (const float*)d_in[7];
  const float* n2g   = (const float*)d_in[8];
  const float* n2b   = (const float*)d_in[9];
  const float* fc1w  = (const float*)d_in[10];
  const float* fc1b  = (const float*)d_in[11];
  const float* fc2w  = (const float*)d_in[12];
  const float* fc2b  = (const float*)d_in[13];

  char* ws = (char*)d_ws;
  // ws layout (bytes); peak ~282 MB (hb reuses q/k/v region)
  bfu* wt_qkv   = (bfu*)(ws + 0);          //  576x192
  bfu* wt_proj  = (bfu*)(ws + 221184);     //  192x192
  bfu* wt_fc1   = (bfu*)(ws + 294912);     //  768x192
  bfu* wt_fc2   = (bfu*)(ws + 589824);     //  192x768
  bfu* tblT     = (bfu*)(ws + 884736);     //  compact bias 6*64*3312 bf16
  bfu* A1       = (bfu*)(ws + 16809984);   //  138240x192  (A1 / attn_out / y2)
  bfu* qb       = (bfu*)(ws + 69894144);   //  q [5760][144][32]
  bfu* kb       = (bfu*)(ws + 122978304);  //  k [5760][144][32]
  bfu* vb       = (bfu*)(ws + 176062464);  //  v^T [5760][32][160]
  bfu* hb       = qb;                      //  h reuses q/k/v (138240x768)
  float* out    = (float*)d_out;           //  doubles as x1 buffer

  wt_kernel<<<432, 256, 0, stream>>>(qkvw, wt_qkv, 192, 576);
  wt_kernel<<<144, 256, 0, stream>>>(projw, wt_proj, 192, 192);
  wt_kernel<<<576, 256, 0, stream>>>(fc1w, wt_fc1, 192, 768);
  wt_kernel<<<576, 256, 0, stream>>>(fc2w, wt_fc2, 768, 192);
  bias2_kernel<<<4968, 256, 0, stream>>>(tbl, tblT);
  vpad_kernel<<<5760, 256, 0, stream>>>((unsigned int*)vb);
  ln1_kernel<<<34560, 256, 0, stream>>>(x, n1g, n1b, A1);
  gemm_kernel<<<1080, 256, 0, stream>>>(A1, wt_qkv, qkvb, 192, 6, 0,
                                        nullptr, qb, kb, vb);
  attn_kernel<<<dim3(64, 3, 15), 256, 0, stream>>>(qb, kb, vb, tblT, A1);
  gemm_kernel<<<1080, 256, 0, stream>>>(A1, wt_proj, projb, 192, 2, 1,
                                        x, out, nullptr, nullptr);
  ln2_kernel<<<34560, 256, 0, stream>>>(out, n2g, n2b, A1);
  gemm_kernel<<<1080, 256, 0, stream>>>(A1, wt_fc1, fc1b, 192, 8, 2,
                                        nullptr, hb, nullptr, nullptr);
  gemm_kernel<<<1080, 256, 0, stream>>>(hb, wt_fc2, fc2b, 768, 2, 3,
                                        out, out, nullptr, nullptr);
}

// Round 7
// 964.672 us; speedup vs baseline: 1.6624x; 1.6624x over previous
//
#include <hip/hip_runtime.h>

// ---------------------------------------------------------------------------
// Earth-specific transformer block (Pangu/swin style) for MI355X gfx950.
// DIM=192, HEADS=6 (d=32), RES=(8,96,180), WIN=(2,6,12), SHIFT=(1,3,6), MLP=4x
// All GEMMs in bf16 MFMA (16x16x32), fp32 accumulate. Output fp32.
// R7: GEMM = one (M-panel, N-tile) per block, XCD-chunked M-major swizzle:
//     all NT blocks sharing an A-panel run concurrently on the SAME XCD ->
//     A fetched once per XCD into L2 (R6's 6-8x A re-fetch eliminated).
//     Inner loop = R4's verified BK=64 A+B global_load_lds staging.
//     attn unchanged from R5.
// ---------------------------------------------------------------------------

typedef __attribute__((ext_vector_type(8))) short short8;
typedef __attribute__((ext_vector_type(4))) short short4v;
typedef __attribute__((ext_vector_type(4))) float floatx4;
typedef unsigned short bfu;   // raw bf16 bits

#define GLOAD_LDS16(g, l)                                            \
  __builtin_amdgcn_global_load_lds(                                  \
      (const __attribute__((address_space(1))) unsigned int*)(g),    \
      (__attribute__((address_space(3))) unsigned int*)(l), 16, 0, 0)

__device__ __forceinline__ bfu f2bf(float f) {
  unsigned int u = __builtin_bit_cast(unsigned int, f);
  u += 0x7fffu + ((u >> 16) & 1u);        // round-to-nearest-even
  return (bfu)(u >> 16);
}
__device__ __forceinline__ float bf2f(bfu s) {
  return __builtin_bit_cast(float, (unsigned int)s << 16);
}

// --- transpose fp32 (K x N) -> bf16 (N x K) --------------------------------
__global__ void wt_kernel(const float* __restrict__ src, bfu* __restrict__ dst,
                          int K, int N) {
  int idx = blockIdx.x * 256 + threadIdx.x;
  if (idx >= K * N) return;
  int k = idx / N, n = idx % N;
  dst[(size_t)n * K + k] = f2bf(src[idx]);
}

// --- compact bias: tblT[h][w][3312] bf16 from table[ep][w][h] fp32 ---------
__global__ void bias2_kernel(const float* __restrict__ table,
                             bfu* __restrict__ out) {
  int idx = blockIdx.x * 256 + threadIdx.x;
  if (idx >= 1271808) return;                    // 6*64*3312
  int h = idx / 211968;
  int r = idx % 211968;
  int w = r / 3312, ep = r % 3312;
  out[idx] = f2bf(table[(size_t)ep * 384 + w * 6 + h]);
}

// --- zero the m=144..159 pad columns of the transposed V buffer ------------
__global__ void vpad_kernel(unsigned int* __restrict__ vbw) {
  int tid = threadIdx.x;
  int dd = tid >> 3, c = tid & 7;
  vbw[(size_t)blockIdx.x * 2560 + dd * 80 + 72 + c] = 0;
}

// --- LN1 + roll(-shift) + window-partition gather -> bf16 A1 ---------------
__global__ __launch_bounds__(256) void ln1_kernel(
    const float* __restrict__ x, const float* __restrict__ g,
    const float* __restrict__ be, bfu* __restrict__ A1) {
  int wv = threadIdx.x >> 6, lane = threadIdx.x & 63;
  int r = blockIdx.x * 4 + wv;
  int n = r % 144, w = (r / 144) & 63, bb = r / 9216;
  int ip = w >> 4, il = w & 15;
  int p1 = n / 72, rem = n % 72, l1 = rem / 12, o1 = rem % 12;
  int pl = ip * 2 + p1 + 1;   if (pl >= 8) pl -= 8;     // rolled pos + shift
  int lat = il * 6 + l1 + 3;  if (lat >= 96) lat -= 96;
  int lon = bb * 12 + o1 + 6; if (lon >= 180) lon -= 180;
  size_t t = (size_t)(pl * 96 + lat) * 180 + lon;
  const float* xr = x + t * 192;
  float v0 = xr[lane], v1 = xr[lane + 64], v2 = xr[lane + 128];
  float s = v0 + v1 + v2;
  #pragma unroll
  for (int o = 32; o; o >>= 1) s += __shfl_xor(s, o);
  float mu = s * (1.0f / 192.0f);
  float d0 = v0 - mu, d1 = v1 - mu, d2 = v2 - mu;
  float q2 = d0 * d0 + d1 * d1 + d2 * d2;
  #pragma unroll
  for (int o = 32; o; o >>= 1) q2 += __shfl_xor(q2, o);
  float rstd = rsqrtf(q2 * (1.0f / 192.0f) + 1e-5f);
  bfu* orow = A1 + (size_t)r * 192;
  orow[lane]       = f2bf(d0 * rstd * g[lane]       + be[lane]);
  orow[lane + 64]  = f2bf(d1 * rstd * g[lane + 64]  + be[lane + 64]);
  orow[lane + 128] = f2bf(d2 * rstd * g[lane + 128] + be[lane + 128]);
}

// --- LN2 (natural rows) -> bf16 --------------------------------------------
__global__ __launch_bounds__(256) void ln2_kernel(
    const float* __restrict__ xin, const float* __restrict__ g,
    const float* __restrict__ be, bfu* __restrict__ yout) {
  int wv = threadIdx.x >> 6, lane = threadIdx.x & 63;
  size_t r = (size_t)blockIdx.x * 4 + wv;
  const float* xr = xin + r * 192;
  float v0 = xr[lane], v1 = xr[lane + 64], v2 = xr[lane + 128];
  float s = v0 + v1 + v2;
  #pragma unroll
  for (int o = 32; o; o >>= 1) s += __shfl_xor(s, o);
  float mu = s * (1.0f / 192.0f);
  float d0 = v0 - mu, d1 = v1 - mu, d2 = v2 - mu;
  float q2 = d0 * d0 + d1 * d1 + d2 * d2;
  #pragma unroll
  for (int o = 32; o; o >>= 1) q2 += __shfl_xor(q2, o);
  float rstd = rsqrtf(q2 * (1.0f / 192.0f) + 1e-5f);
  bfu* orow = yout + r * 192;
  orow[lane]       = f2bf(d0 * rstd * g[lane]       + be[lane]);
  orow[lane + 64]  = f2bf(d1 * rstd * g[lane + 64]  + be[lane + 64]);
  orow[lane + 128] = f2bf(d2 * rstd * g[lane + 128] + be[lane + 128]);
}

// --- MFMA GEMM: one (128-row M-panel, 96-col N-tile) per block -------------
// grid = 1080*NT blocks (1-D). XCD-chunked M-major swizzle: work =
// (bid%8)*(W/8) + bid/8; m_panel = work/NT, nt = work%NT. All NT blocks of
// an M-panel run concurrently on one XCD -> A-panel fetched once into L2.
// 4 waves, wave tile 32x96 (acc[2][6]). BK=64: A (128x64) + B (96x64)
// async-staged to LDS via global_load_lds(16B), XOR slot swizzle, 2 barriers
// per chunk. LDS 28 KB -> 4+ blocks/CU.
// mode 0: qkv scatter (+bias): q pre-scaled -> [win][n][32]; k -> same;
//         v TRANSPOSED -> [win][dd][160] (pad cols zeroed by vpad_kernel)
// mode 1: proj (+bias) + un-window/un-roll + residual(aux=x) -> fp32 out0
// mode 2: fc1 (+bias) + exact GELU -> bf16 h [row][768], LDS-staged stores
// mode 3: fc2 (+bias) + residual(aux=x1) -> fp32 out0
__global__ __launch_bounds__(256, 4) void gemm_kernel(
    const bfu* __restrict__ A, const bfu* __restrict__ BT,
    const float* __restrict__ bias, int K, int NT, int mode,
    const float* aux, void* out0, void* out1, void* out2) {
  __shared__ __align__(16) short LB[14336];      // 28 KB: As[8192] + Bs[6144]
  short* As = LB;                                // [128][8 slots of 8 shorts]
  short* Bs = LB + 8192;                         // [96][8 slots]
  bfu* E = (bfu*)LB;                             // epilogue tile [128][104]
  const int tid = threadIdx.x;
  const int wv = tid >> 6, lane = tid & 63;
  const int r16 = lane & 15, quad = lane >> 4;
  const int sw = r16 & 7;                        // read-side XOR key

  const int W = gridDim.x;
  const int work = (blockIdx.x & 7) * (W >> 3) + (blockIdx.x >> 3);
  const int m0 = (work / NT) * 128;
  const int n0 = (work % NT) * 96;
  const bfu* Bsrc = BT + (size_t)n0 * K;

  floatx4 acc[2][6];
  #pragma unroll
  for (int s = 0; s < 2; ++s)
    #pragma unroll
    for (int j = 0; j < 6; ++j) acc[s][j] = (floatx4){0.f, 0.f, 0.f, 0.f};

  for (int kc = 0; kc < K; kc += 64) {
    __syncthreads();                           // prev chunk fully read
    // stage A: 1024 16B-chunks (128 rows x 8 slots), 4 per thread
    #pragma unroll
    for (int j = 0; j < 4; ++j) {
      int c = j * 256 + tid;
      int row = c >> 3, l = (c & 7) ^ (row & 7);
      GLOAD_LDS16(A + (size_t)(m0 + row) * K + kc + l * 8, As + c * 8);
    }
    // stage B: 768 16B-chunks (96 rows x 8 slots), 3 per thread
    #pragma unroll
    for (int j = 0; j < 3; ++j) {
      int c = j * 256 + tid;
      int row = c >> 3, l = (c & 7) ^ (row & 7);
      GLOAD_LDS16(Bsrc + (size_t)row * K + kc + l * 8, Bs + c * 8);
    }
    __syncthreads();                           // drains vmcnt -> data ready
    #pragma unroll
    for (int ks = 0; ks < 2; ++ks) {
      const int p8 = ((ks * 4 + quad) ^ sw) * 8;
      short8 a[2], b[6];
      #pragma unroll
      for (int s = 0; s < 2; ++s)
        a[s] = *(const short8*)(As + (wv * 32 + s * 16 + r16) * 64 + p8);
      #pragma unroll
      for (int j = 0; j < 6; ++j)
        b[j] = *(const short8*)(Bs + (j * 16 + r16) * 64 + p8);
      #pragma unroll
      for (int s = 0; s < 2; ++s)
        #pragma unroll
        for (int j = 0; j < 6; ++j)
          acc[s][j] =
              __builtin_amdgcn_mfma_f32_16x16x32_bf16(a[s], b[j], acc[s][j], 0, 0, 0);
    }
  }

  if (mode == 0 || mode == 2) {
    // ---- stage epilogue tile in LDS (bf16), then coalesced 16B stores ----
    __syncthreads();                 // all waves done reading As/Bs
    #pragma unroll
    for (int s = 0; s < 2; ++s) {
      int er = wv * 32 + s * 16 + quad * 4;
      #pragma unroll
      for (int j = 0; j < 6; ++j) {
        int c = j * 16 + r16;
        float bia = bias[n0 + c];
        #pragma unroll
        for (int i = 0; i < 4; ++i) {
          float val = acc[s][j][i] + bia;
          if (mode == 0) {
            if (n0 < 192) val *= 0.17677669529663687f;   // q pre-scale
            E[(er + i) * 104 + c] = f2bf(val);
          } else {
            float ge = 0.5f * val * (1.0f + erff(val * 0.70710678118654752f));
            E[(er + i) * 104 + c] = f2bf(ge);
          }
        }
      }
    }
    __syncthreads();
    if (mode == 2) {
      // h[row][768], 16B chunks: 128 rows x 12 chunks = 1536
      #pragma unroll
      for (int u = 0; u < 6; ++u) {
        int id = u * 256 + tid;
        int r = id / 12, c8 = (id % 12) * 8;
        *(short8*)((bfu*)out0 + (size_t)(m0 + r) * 768 + n0 + c8) =
            *(const short8*)(E + r * 104 + c8);
      }
    } else if (n0 < 384) {
      // q or k: [win][n][32], 16B chunks along dd
      bfu* dst = (bfu*)(n0 < 192 ? out0 : out1);
      #pragma unroll
      for (int u = 0; u < 6; ++u) {
        int id = u * 256 + tid;
        int r = id / 12, c8 = (id % 12) * 8;
        int row = m0 + r;
        int n = row % 144, w = (row / 144) & 63, bb = row / 9216;
        int head = ((n0 + c8) % 192) >> 5, dd = c8 & 31;
        size_t win = (size_t)(bb * 6 + head) * 64 + w;
        *(short8*)(dst + win * 4608 + n * 32 + dd) =
            *(const short8*)(E + r * 104 + c8);
      }
    } else {
      // v transposed: [win][dd][160], 16B chunks along n (8 rows of E)
      #pragma unroll
      for (int u = 0; u < 6; ++u) {
        int id = u * 256 + tid;
        int c = id % 96, k8 = id / 96;
        int r0 = k8 * 8;
        int row0 = m0 + r0;                // multiples of 8; 144%8==0
        int n = row0 % 144, w = (row0 / 144) & 63, bb = row0 / 9216;
        int head = ((n0 + c) % 192) >> 5, dd = c & 31;
        size_t win = (size_t)(bb * 6 + head) * 64 + w;
        short8 t8;
        #pragma unroll
        for (int i = 0; i < 8; ++i) t8[i] = (short)E[(r0 + i) * 104 + c];
        *(short8*)((bfu*)out2 + win * 5120 + dd * 160 + n) = t8;
      }
    }
  } else {
    // ---- direct fp32 epilogue (modes 1 and 3): 64B quad-chunk stores ----
    #pragma unroll
    for (int s = 0; s < 2; ++s) {
      const int row0 = m0 + wv * 32 + s * 16 + quad * 4;
      #pragma unroll
      for (int j = 0; j < 6; ++j) {
        int col = n0 + j * 16 + r16;
        float bia = bias[col];
        #pragma unroll
        for (int i = 0; i < 4; ++i) {
          int row = row0 + i;
          float val = acc[s][j][i] + bia;
          if (mode == 1) {
            int n = row % 144, w = (row / 144) & 63, bb = row / 9216;
            int ip = w >> 4, il = w & 15;
            int p1 = n / 72, rem = n % 72, l1 = rem / 12, o1 = rem % 12;
            int pl = ip * 2 + p1 + 1;   if (pl >= 8) pl -= 8;
            int lat = il * 6 + l1 + 3;  if (lat >= 96) lat -= 96;
            int lon = bb * 12 + o1 + 6; if (lon >= 180) lon -= 180;
            size_t t = (size_t)(pl * 96 + lat) * 180 + lon;
            ((float*)out0)[t * 192 + col] = aux[t * 192 + col] + val;
          } else {
            size_t idx = (size_t)row * 192 + col;
            ((float*)out0)[idx] = aux[idx] + val;
          }
        }
      }
    }
  }
}

// --- windowed attention: one block per (b, head-pair, w) --------------------
// (unchanged from R5)
__global__ __launch_bounds__(256) void attn_kernel(
    const bfu* __restrict__ qg_, const bfu* __restrict__ kg_,
    const bfu* __restrict__ vg_, const bfu* __restrict__ tblT,
    bfu* __restrict__ aout) {
  __shared__ __align__(16) bfu Ss[144 * 148];   // 42.6 KB
  __shared__ __align__(16) bfu bias_l[3312];    // 6.6 KB slice
  __shared__ unsigned short rn[144];            // row bias index part
  __shared__ short cm[144];                     // col bias index part
  __shared__ unsigned char regs[144];           // shift-mask region ids

  const int w = blockIdx.x, h0 = blockIdx.y * 2, b = blockIdx.z;
  const int tid = threadIdx.x;
  const int wv = tid >> 6, lane = tid & 63, r16 = lane & 15, quad = lane >> 4;

  if (tid < 144) {
    int n = tid;
    int p1 = n / 72, rem = n % 72, l1 = rem / 12, o1 = rem % 12;
    rn[n] = (unsigned short)(828 * p1 + 23 * l1 + o1 + 11);
    cm[n] = (short)(1656 * p1 + 138 * l1 - o1);
    int ip = w >> 4, il = w & 15;
    int pl = ip * 2 + p1, lat = il * 6 + l1, lon = b * 12 + o1;
    int rp = pl < 6 ? 0 : (pl < 7 ? 1 : 2);
    int rl = lat < 90 ? 0 : (lat < 93 ? 1 : 2);
    int ro = lon < 174 ? 0 : 1;
    regs[n] = (unsigned char)(rp * 9 + rl * 3 + ro);
  }

  // async-stage bias slice for head h0 (414 x 16B chunks)
  {
    const bfu* bsrc = tblT + (size_t)(h0 * 64 + w) * 3312;
    GLOAD_LDS16(bsrc + tid * 8, bias_l + tid * 8);
    if (tid < 158) GLOAD_LDS16(bsrc + (256 + tid) * 8, bias_l + (256 + tid) * 8);
  }

  short4v ov[2][5];
  #pragma unroll
  for (int hh = 0; hh < 2; ++hh) {
    const int h = h0 + hh;
    const size_t win = (size_t)((b * 6 + h) * 64 + w);
    const bfu* qg = qg_ + win * 4608;
    const bfu* kg = kg_ + win * 4608;
    const bfu* vt = vg_ + win * 5120;

    // Phase 1: S = Q K^T (Q pre-scaled). 81 tiles.
    #pragma unroll 3
    for (int u = 0; u < 21; ++u) {
      int t = wv * 21 + u;
      if (t < 81) {
        int tn = t / 9, tm = t % 9;
        short8 a  = *(const short8*)(qg + (tn * 16 + r16) * 32 + quad * 8);
        short8 bo = *(const short8*)(kg + (tm * 16 + r16) * 32 + quad * 8);
        floatx4 z = (floatx4){0.f, 0.f, 0.f, 0.f};
        floatx4 d = __builtin_amdgcn_mfma_f32_16x16x32_bf16(a, bo, z, 0, 0, 0);
        int m = tm * 16 + r16;
        #pragma unroll
        for (int i = 0; i < 4; ++i)
          Ss[(tn * 16 + quad * 4 + i) * 148 + m] = f2bf(d[i]);
      }
    }
    __syncthreads();   // S ready; bias slice loaded; tables ready

    // Phase 2: softmax + bias(LDS) + mask.
    for (int rb = 0; rb < 9; ++rb) {
      int rr = rb * 16 + wv * 4 + quad;
      unsigned char rgn = regs[rr];
      int rnv = rn[rr];
      const bfu* srow = Ss + rr * 148;
      float v[9];
      float mx = -1e30f;
      #pragma unroll
      for (int j = 0; j < 9; ++j) {
        int c = r16 + 16 * j;
        float s = bf2f(srow[c]) + bf2f(bias_l[rnv + cm[c]]);
        if (regs[c] != rgn) s -= 100.0f;
        v[j] = s;
        mx = fmaxf(mx, s);
      }
      #pragma unroll
      for (int o = 8; o; o >>= 1) mx = fmaxf(mx, __shfl_xor(mx, o));
      float sum = 0.f;
      #pragma unroll
      for (int j = 0; j < 9; ++j) { v[j] = __expf(v[j] - mx); sum += v[j]; }
      #pragma unroll
      for (int o = 8; o; o >>= 1) sum += __shfl_xor(sum, o);
      float inv = 1.0f / sum;
      bfu* wrow = Ss + rr * 148;
      #pragma unroll
      for (int j = 0; j < 9; ++j) wrow[r16 + 16 * j] = f2bf(v[j] * inv);
    }
    __syncthreads();   // P ready; bias_l reads done

    if (hh == 0) {     // overlap next head's bias load with PV
      const bfu* bsrc = tblT + (size_t)((h0 + 1) * 64 + w) * 3312;
      GLOAD_LDS16(bsrc + tid * 8, bias_l + tid * 8);
      if (tid < 158) GLOAD_LDS16(bsrc + (256 + tid) * 8, bias_l + (256 + tid) * 8);
    }

    // Phase 3: O = P V, operand-swapped -> D[dd][n]; pack rows as short4.
    short8 bfr[2][5];
    #pragma unroll
    for (int td = 0; td < 2; ++td)
      #pragma unroll
      for (int km = 0; km < 5; ++km)
        bfr[td][km] =
            *(const short8*)(vt + (td * 16 + r16) * 160 + km * 32 + quad * 8);

    #pragma unroll
    for (int u = 0; u < 5; ++u) {
      int t = wv * 5 + u;
      if (t < 18) {
        int tn = t >> 1, td = t & 1;
        floatx4 acc = (floatx4){0.f, 0.f, 0.f, 0.f};
        #pragma unroll
        for (int km = 0; km < 5; ++km) {
          short8 a;
          if (km == 4 && quad >= 2) {
            a = (short8)(short)0;          // P cols 144..159 are zero
          } else {
            const bfu* ap = Ss + (tn * 16 + r16) * 148 + km * 32 + quad * 8;
            *(short4v*)&a       = *(const short4v*)ap;
            *((short4v*)&a + 1) = *(const short4v*)(ap + 4);
          }
          acc = __builtin_amdgcn_mfma_f32_16x16x32_bf16(bfr[td][km], a, acc, 0, 0, 0);
        }
        short4v o;
        #pragma unroll
        for (int i = 0; i < 4; ++i) o[i] = (short)f2bf(acc[i]);
        ov[hh][u] = o;
      }
    }
    if (hh == 0) __syncthreads();   // Ss reads done before next head's phase 1
  }

  // store both heads together: full 128B lines per row
  const size_t orow = (size_t)((b * 64 + w) * 144) * 192 + h0 * 32;
  #pragma unroll
  for (int u = 0; u < 5; ++u) {
    int t = wv * 5 + u;
    if (t < 18) {
      int tn = t >> 1, td = t & 1;
      size_t a0 = orow + (size_t)(tn * 16 + r16) * 192 + td * 16 + quad * 4;
      *(short4v*)(aout + a0)      = ov[0][u];
      *(short4v*)(aout + a0 + 32) = ov[1][u];
    }
  }
}

// ---------------------------------------------------------------------------
extern "C" void kernel_launch(void* const* d_in, const int* in_sizes, int n_in,
                              void* d_out, int out_size, void* d_ws, size_t ws_size,
                              hipStream_t stream) {
  (void)in_sizes; (void)n_in; (void)out_size; (void)ws_size;
  const float* x     = (const float*)d_in[0];
  const float* n1g   = (const float*)d_in[1];
  const float* n1b   = (const float*)d_in[2];
  const float* qkvw  = (const float*)d_in[3];
  const float* qkvb  = (const float*)d_in[4];
  const float* tbl   = (const float*)d_in[5];
  const float* projw = (const float*)d_in[6];
  const float* projb = (const float*)d_in[7];
  const float* n2g   = (const float*)d_in[8];
  const float* n2b   = (const float*)d_in[9];
  const float* fc1w  = (const float*)d_in[10];
  const float* fc1b  = (const float*)d_in[11];
  const float* fc2w  = (const float*)d_in[12];
  const float* fc2b  = (const float*)d_in[13];

  char* ws = (char*)d_ws;
  // ws layout (bytes); peak ~282 MB (hb reuses q/k/v region)
  bfu* wt_qkv   = (bfu*)(ws + 0);          //  576x192
  bfu* wt_proj  = (bfu*)(ws + 221184);     //  192x192
  bfu* wt_fc1   = (bfu*)(ws + 294912);     //  768x192
  bfu* wt_fc2   = (bfu*)(ws + 589824);     //  192x768
  bfu* tblT     = (bfu*)(ws + 884736);     //  compact bias 6*64*3312 bf16
  bfu* A1       = (bfu*)(ws + 16809984);   //  138240x192  (A1 / attn_out / y2)
  bfu* qb       = (bfu*)(ws + 69894144);   //  q [5760][144][32]
  bfu* kb       = (bfu*)(ws + 122978304);  //  k [5760][144][32]
  bfu* vb       = (bfu*)(ws + 176062464);  //  v^T [5760][32][160]
  bfu* hb       = qb;                      //  h reuses q/k/v (138240x768)
  float* out    = (float*)d_out;           //  doubles as x1 buffer

  wt_kernel<<<432, 256, 0, stream>>>(qkvw, wt_qkv, 192, 576);
  wt_kernel<<<144, 256, 0, stream>>>(projw, wt_proj, 192, 192);
  wt_kernel<<<576, 256, 0, stream>>>(fc1w, wt_fc1, 192, 768);
  wt_kernel<<<576, 256, 0, stream>>>(fc2w, wt_fc2, 768, 192);
  bias2_kernel<<<4968, 256, 0, stream>>>(tbl, tblT);
  vpad_kernel<<<5760, 256, 0, stream>>>((unsigned int*)vb);
  ln1_kernel<<<34560, 256, 0, stream>>>(x, n1g, n1b, A1);
  gemm_kernel<<<6480, 256, 0, stream>>>(A1, wt_qkv, qkvb, 192, 6, 0,
                                        nullptr, qb, kb, vb);
  attn_kernel<<<dim3(64, 3, 15), 256, 0, stream>>>(qb, kb, vb, tblT, A1);
  gemm_kernel<<<2160, 256, 0, stream>>>(A1, wt_proj, projb, 192, 2, 1,
                                        x, out, nullptr, nullptr);
  ln2_kernel<<<34560, 256, 0, stream>>>(out, n2g, n2b, A1);
  gemm_kernel<<<8640, 256, 0, stream>>>(A1, wt_fc1, fc1b, 192, 8, 2,
                                        nullptr, hb, nullptr, nullptr);
  gemm_kernel<<<2160, 256, 0, stream>>>(hb, wt_fc2, fc2b, 768, 2, 3,
                                        out, out, nullptr, nullptr);
}